// Round 1
// baseline (562.968 us; speedup 1.0000x reference)
//
#include <hip/hip_runtime.h>
#include <hip/hip_bf16.h>
#include <math.h>

// Pipeline:
//  K0 cvt       : wq, wout -> bf16; conv_w [o][i][k] -> 3x bf16 W_k[o][i]
//  K1 pat_kv    : pat2 = LN(LN(pattern)); kv = pat2 @ wkv^T (fp32 VALU, tiny)
//                 -> k_bf [h][4 chunks][128 rows][8 units] bf16, XOR-swizzled
//                    (d-cols perm32'd, scaled by 0.125 — exact in bf16)
//                 -> v_t  [h][4 chunks][64 rows][16 units] bf16, XOR-swizzled
//                    (pattern-cols perm32'd)
//  K2 conv_ln   : y = sum_k Xshift_k @ W_k^T (MFMA) + b + x, leaky, LN -> xn_bf
//  K3 qattn     : FUSED q-proj + S^T-orientation MFMA attention       -> ao_bf
//                 128 rows/block (32 queries/wave), double-buffered
//                 global_load_lds staging of pre-swizzled chunks, 1 barrier/chunk
//  K4 outproj_ln: ao @ wout^T (MFMA) + bout, LN                       -> d_out
//
// T=65536, D=256, P=512, H=8, dA=64, seqlen=2048.
// perm32(c) permutes bits 2..4: (b4,b3,b2) -> (b2,b4,b3); inv32 is its inverse.
// Chunk image (16 KB): K rows 128B, 16B unit u at phys (u ^ (row&7));
//                      V^T rows 256B, 16B unit u at phys (u ^ (row&15)).
// Swizzle is baked into the GLOBAL layout so LDS staging is a linear copy
// (global_load_lds writes wave-uniform base + lane*16) and fragment ds_reads
// spread over all 32 banks (2-way = free).

#define EPSF 1e-5f

typedef short  s16x8 __attribute__((ext_vector_type(8)));
typedef short  s16x4 __attribute__((ext_vector_type(4)));
typedef float  f32x4 __attribute__((ext_vector_type(4)));

typedef __attribute__((address_space(3))) unsigned int       lds_u32_t;
typedef __attribute__((address_space(1))) const unsigned int glb_u32_t;

__device__ __forceinline__ void gload_lds16(const void* g, void* l) {
    __builtin_amdgcn_global_load_lds((glb_u32_t*)g, (lds_u32_t*)l, 16, 0, 0);
}

__device__ __forceinline__ unsigned short f2bf(float f) {
    union { float f; unsigned u; } v; v.f = f;
    unsigned r = (v.u + 0x7fffu + ((v.u >> 16) & 1u)) >> 16;   // RNE
    return (unsigned short)r;
}
__device__ __forceinline__ float bf2f(unsigned short h) {
    union { unsigned u; float f; } v; v.u = ((unsigned)h) << 16;
    return v.f;
}
__device__ __forceinline__ unsigned fbits(float f) {
    union { float f; unsigned u; } v; v.f = f; return v.u;
}
// pack two floats' high halves (truncate-to-bf16): low16 = lo, high16 = hi
__device__ __forceinline__ unsigned pk_hi(float lo, float hi) {
    return __builtin_amdgcn_perm(fbits(hi), fbits(lo), 0x07060302u);
}
__device__ __forceinline__ int inv32(int t) {   // inverse of perm32, touches bits 2..4
    return (t & ~31) | ((t & 0x0C) << 1) | ((t & 0x10) >> 2) | (t & 3);
}

union Bfrag { unsigned u[4]; s16x8 s; };

// ---------------------------------------------------------------- K0
__global__ void cvt_kernel(const float* __restrict__ wq,
                           const float* __restrict__ wout,
                           const float* __restrict__ cw,
                           short* __restrict__ wq_bf,
                           short* __restrict__ wout_bf,
                           short* __restrict__ wck) {
    const int b = blockIdx.x, tid = threadIdx.x;
    if (b < 256) {
        const int i = ((b & 127) * 256 + tid) * 4;
        const float* src = (b < 128) ? wq : wout;
        short* dst = (b < 128) ? wq_bf : wout_bf;
        const float4 x = *(const float4*)(src + i);
        s16x4 o; o[0] = f2bf(x.x); o[1] = f2bf(x.y); o[2] = f2bf(x.z); o[3] = f2bf(x.w);
        *(s16x4*)(dst + i) = o;
    } else {
        const int idx = (b - 256) * 256 + tid;          // (o,i) pair, 65536 total
        const float* p = cw + (size_t)idx * 3;
        wck[idx]              = (short)f2bf(p[0]);
        wck[65536 + idx]      = (short)f2bf(p[1]);
        wck[131072 + idx]     = (short)f2bf(p[2]);
    }
}

// ---------------------------------------------------------------- K1
__global__ void pat_kv_kernel(const float* __restrict__ pattern,
                              const float* __restrict__ wkv,
                              short* __restrict__ k_bf,    // swizzled chunk images
                              short* __restrict__ v_t) {   // swizzled chunk images
    __shared__ __align__(16) float spat[256];
    __shared__ float scr[4];
    const int w = blockIdx.x;
    const int tid = threadIdx.x;
    const int lane = tid & 63, wav = tid >> 6;

    float v = pattern[(size_t)w * 256 + tid];

    float s = v;
    #pragma unroll
    for (int off = 32; off; off >>= 1) s += __shfl_xor(s, off);
    if (lane == 0) scr[wav] = s;
    __syncthreads();
    float mu = (scr[0] + scr[1] + scr[2] + scr[3]) * (1.f / 256.f);
    __syncthreads();
    float d = v - mu;
    float s2 = d * d;
    #pragma unroll
    for (int off = 32; off; off >>= 1) s2 += __shfl_xor(s2, off);
    if (lane == 0) scr[wav] = s2;
    __syncthreads();
    float var = (scr[0] + scr[1] + scr[2] + scr[3]) * (1.f / 256.f);
    float x1 = d * rsqrtf(var + EPSF);
    __syncthreads();

    s = x1;
    #pragma unroll
    for (int off = 32; off; off >>= 1) s += __shfl_xor(s, off);
    if (lane == 0) scr[wav] = s;
    __syncthreads();
    mu = (scr[0] + scr[1] + scr[2] + scr[3]) * (1.f / 256.f);
    __syncthreads();
    d = x1 - mu;
    s2 = d * d;
    #pragma unroll
    for (int off = 32; off; off >>= 1) s2 += __shfl_xor(s2, off);
    if (lane == 0) scr[wav] = s2;
    __syncthreads();
    var = (scr[0] + scr[1] + scr[2] + scr[3]) * (1.f / 256.f);
    float x2 = d * rsqrtf(var + EPSF);

    spat[tid] = x2;
    __syncthreads();

    #pragma unroll
    for (int u = 0; u < 4; u++) {
        const int j = tid + 256 * u;                 // 0..1023
        const float* wr = wkv + (size_t)j * 256;
        float acc = 0.f;
        for (int i4 = 0; i4 < 64; i4++) {
            float4 w4 = *(const float4*)(wr + i4 * 4);
            float4 x4 = *(const float4*)(&spat[i4 * 4]);
            acc += w4.x * x4.x + w4.y * x4.y + w4.z * x4.z + w4.w * x4.w;
        }
        const int h = j >> 7, r = j & 127;
        if (r < 64) {
            // K: pattern row = w, d k-position c = inv32(r); scale by 0.125 (exact)
            const int c = inv32(r);
            const int ck = w >> 7, crow = w & 127;
            const int un = c >> 3, ph = un ^ (crow & 7);
            k_bf[(size_t)h * 32768 + ck * 8192 + crow * 64 + ph * 8 + (c & 7)]
                = (short)f2bf(acc * 0.125f);
        } else {
            // V^T: d row = r-64, pattern k-position c = inv32(w)
            const int rd = r - 64;
            const int c = inv32(w);
            const int ck = c >> 7, cc = c & 127;
            const int un = cc >> 3, ph = un ^ (rd & 15);
            v_t[(size_t)h * 32768 + ck * 8192 + rd * 128 + ph * 8 + (cc & 7)]
                = (short)f2bf(acc);
        }
    }
}

// ---------------------------------------------------------------- K2: conv as 3 shifted MFMA GEMMs
__global__ __launch_bounds__(256, 4)
void conv_ln_kernel(const float* __restrict__ x,
                    const short* __restrict__ wck,   // [3][256][256] bf16
                    const float* __restrict__ cb,
                    short* __restrict__ xn_bf) {
    __shared__ __align__(16) short xs[66 * 268];
    const int tid = threadIdx.x;
    const int r0 = blockIdx.x * 64;
    const int pos0 = r0 & 2047;

    #pragma unroll
    for (int it = 0; it < 17; it++) {
        const int idx = tid + it * 256;              // float4 index, 4224 total
        if (idx < 4224) {
            const int row = idx >> 6, c4 = idx & 63;
            float4 v = {0.f, 0.f, 0.f, 0.f};
            if (pos0 - 2 + row >= 0)
                v = *(const float4*)(x + (size_t)(r0 - 2 + row) * 256 + c4 * 4);
            s16x4 o; o[0] = f2bf(v.x); o[1] = f2bf(v.y); o[2] = f2bf(v.z); o[3] = f2bf(v.w);
            *(s16x4*)(xs + row * 268 + c4 * 4) = o;
        }
    }
    __syncthreads();

    const int lane = tid & 63, w = tid >> 6, g = lane >> 4, cl = lane & 15;

    f32x4 acc[4][4];
    #pragma unroll
    for (int mt = 0; mt < 4; mt++)
        #pragma unroll
        for (int nt = 0; nt < 4; nt++) acc[mt][nt] = (f32x4){0.f, 0.f, 0.f, 0.f};

    #pragma unroll
    for (int kk = 0; kk < 3; kk++) {
        const short* wb = wck + kk * 65536;
        for (int s = 0; s < 8; s++) {
            s16x8 a[4];
            #pragma unroll
            for (int mt = 0; mt < 4; mt++)
                a[mt] = *(const s16x8*)(xs + (mt * 16 + cl + kk) * 268 + s * 32 + g * 8);
            #pragma unroll
            for (int nt = 0; nt < 4; nt++) {
                const s16x8 b = *(const s16x8*)(wb + (size_t)(w * 64 + nt * 16 + cl) * 256 + s * 32 + g * 8);
                #pragma unroll
                for (int mt = 0; mt < 4; mt++)
                    acc[mt][nt] = __builtin_amdgcn_mfma_f32_16x16x32_bf16(a[mt], b, acc[mt][nt], 0, 0, 0);
            }
        }
    }

    #pragma unroll
    for (int nt = 0; nt < 4; nt++) {
        const int col = w * 64 + nt * 16 + cl;
        const float b = cb[col];
        #pragma unroll
        for (int mt = 0; mt < 4; mt++)
            #pragma unroll
            for (int r = 0; r < 4; r++) {
                const int row = mt * 16 + g * 4 + r;
                float y = acc[mt][nt][r] + b + x[(size_t)(r0 + row) * 256 + col];
                acc[mt][nt][r] = (y >= 0.f) ? y : 0.01f * y;
            }
    }
    __syncthreads();
    #pragma unroll
    for (int mt = 0; mt < 4; mt++)
        #pragma unroll
        for (int nt = 0; nt < 4; nt++)
            #pragma unroll
            for (int r = 0; r < 4; r++)
                xs[(mt * 16 + g * 4 + r) * 268 + w * 64 + nt * 16 + cl] =
                    (short)f2bf(acc[mt][nt][r]);
    __syncthreads();

    for (int q = 0; q < 16; q++) {
        const int m = w * 16 + q;
        const s16x4 v4 = *(const s16x4*)(xs + m * 268 + lane * 4);
        const float f0 = bf2f((unsigned short)v4[0]), f1 = bf2f((unsigned short)v4[1]);
        const float f2 = bf2f((unsigned short)v4[2]), f3 = bf2f((unsigned short)v4[3]);
        float s = f0 + f1 + f2 + f3;
        #pragma unroll
        for (int off = 32; off; off >>= 1) s += __shfl_xor(s, off);
        const float mu = s * (1.f / 256.f);
        const float d0 = f0 - mu, d1 = f1 - mu, d2 = f2 - mu, d3 = f3 - mu;
        float vv = d0 * d0 + d1 * d1 + d2 * d2 + d3 * d3;
        #pragma unroll
        for (int off = 32; off; off >>= 1) vv += __shfl_xor(vv, off);
        const float rs = rsqrtf(vv * (1.f / 256.f) + EPSF);
        s16x4 o; o[0] = f2bf(d0 * rs); o[1] = f2bf(d1 * rs);
        o[2] = f2bf(d2 * rs); o[3] = f2bf(d3 * rs);
        *(s16x4*)(xn_bf + (size_t)(r0 + m) * 256 + lane * 4) = o;
    }
}

// ---------------------------------------------------------------- K3: fused q-proj + attention
// Grid T/128. Block: 4 waves; wave w owns queries [r0+32w, +32) as 2 groups of 16.
// Heads looped inside; (head, chunk) flattened to 32 double-buffered stage steps.
// Staging: global_load_lds 16B, linear into LDS (layout pre-swizzled in global),
// issued right after the barrier so L2 latency hides under the chunk's compute.
__global__ __launch_bounds__(256, 2)
void qattn_kernel(const short* __restrict__ xn_bf,
                  const short* __restrict__ wq_bf,
                  const short* __restrict__ k_bf,
                  const short* __restrict__ v_t,
                  short* __restrict__ ao_bf) {
    __shared__ __align__(16) char smem[65536];   // 2 x (16KB K + 16KB V^T)

    const int tid = threadIdx.x;
    const int lane = tid & 63, w = tid >> 6, g = lane >> 4, cl = lane & 15;
    const int r0 = blockIdx.x * 128;
    const int q0 = r0 + w * 32 + cl;             // group-0 query row (group-1 = +16)

    // staging role: waves 0,1 copy K halves; waves 2,3 copy V halves (8KB each)
    const char* kv_base = (w < 2) ? (const char*)k_bf : (const char*)v_t;
    const int   half    = (w & 1) * 8192;

    // preflight: stage (h=0, ck=0) into buf 0
    {
        const char* src = kv_base + half + lane * 16;
        char* dst = smem + w * 8192;
        #pragma unroll
        for (int i = 0; i < 8; i++)
            gload_lds16(src + i * 1024, dst + i * 1024);
    }

    for (int h = 0; h < 8; ++h) {
        // ---- q-projection, both groups (C-layout == scores B-frag, d-permuted)
        f32x4 qacc[2][4];
        #pragma unroll
        for (int u = 0; u < 2; u++)
            #pragma unroll
            for (int nt = 0; nt < 4; nt++) qacc[u][nt] = (f32x4){0.f, 0.f, 0.f, 0.f};
        for (int s = 0; s < 8; ++s) {
            const s16x8 bx0 = *(const s16x8*)(xn_bf + (size_t)q0 * 256 + s * 32 + g * 8);
            const s16x8 bx1 = *(const s16x8*)(xn_bf + ((size_t)q0 + 16) * 256 + s * 32 + g * 8);
            #pragma unroll
            for (int nt = 0; nt < 4; ++nt) {
                const s16x8 aw = *(const s16x8*)(wq_bf + (size_t)(h * 64 + nt * 16 + cl) * 256 + s * 32 + g * 8);
                qacc[0][nt] = __builtin_amdgcn_mfma_f32_16x16x32_bf16(aw, bx0, qacc[0][nt], 0, 0, 0);
                qacc[1][nt] = __builtin_amdgcn_mfma_f32_16x16x32_bf16(aw, bx1, qacc[1][nt], 0, 0, 0);
            }
        }
        Bfrag qB[2][2];
        #pragma unroll
        for (int u = 0; u < 2; ++u)
            #pragma unroll
            for (int s = 0; s < 2; ++s) {
                qB[u][s].u[0] = pk_hi(qacc[u][2 * s][0],     qacc[u][2 * s][1]);
                qB[u][s].u[1] = pk_hi(qacc[u][2 * s][2],     qacc[u][2 * s][3]);
                qB[u][s].u[2] = pk_hi(qacc[u][2 * s + 1][0], qacc[u][2 * s + 1][1]);
                qB[u][s].u[3] = pk_hi(qacc[u][2 * s + 1][2], qacc[u][2 * s + 1][3]);
            }

        float lsum[2] = {0.f, 0.f};
        f32x4 oacc[2][4];
        #pragma unroll
        for (int u = 0; u < 2; u++)
            #pragma unroll
            for (int nd = 0; nd < 4; nd++) oacc[u][nd] = (f32x4){0.f, 0.f, 0.f, 0.f};

        for (int ck = 0; ck < 4; ++ck) {
            const int step = h * 4 + ck;
            const int buf = step & 1;
            __syncthreads();                       // stage(step) done; buf^1 free
            if (step + 1 < 32) {                   // prefetch next chunk into buf^1
                const int ns = step + 1;
                const char* src = kv_base + (size_t)(ns >> 2) * 65536
                                + (ns & 3) * 16384 + half + lane * 16;
                char* dst = smem + (buf ^ 1) * 32768 + w * 8192;
                #pragma unroll
                for (int i = 0; i < 8; i++)
                    gload_lds16(src + i * 1024, dst + i * 1024);
            }
            const char* kc = smem + buf * 32768;
            const char* vc = kc + 16384;

            // scores S^T: 8 pattern-tiles x K=64 (2 steps), both query groups
            f32x4 sa[2][8];
            #pragma unroll
            for (int u = 0; u < 2; u++)
                #pragma unroll
                for (int nt = 0; nt < 8; nt++) sa[u][nt] = (f32x4){0.f, 0.f, 0.f, 0.f};
            #pragma unroll
            for (int nt = 0; nt < 8; nt++) {
                const char* kb = kc + ((nt * 16 + cl) << 7);
                const s16x8 a0 = *(const s16x8*)(kb + ((g       ^ (cl & 7)) << 4));
                const s16x8 a1 = *(const s16x8*)(kb + (((4 + g) ^ (cl & 7)) << 4));
                sa[0][nt] = __builtin_amdgcn_mfma_f32_16x16x32_bf16(a0, qB[0][0].s, sa[0][nt], 0, 0, 0);
                sa[0][nt] = __builtin_amdgcn_mfma_f32_16x16x32_bf16(a1, qB[0][1].s, sa[0][nt], 0, 0, 0);
                sa[1][nt] = __builtin_amdgcn_mfma_f32_16x16x32_bf16(a0, qB[1][0].s, sa[1][nt], 0, 0, 0);
                sa[1][nt] = __builtin_amdgcn_mfma_f32_16x16x32_bf16(a1, qB[1][1].s, sa[1][nt], 0, 0, 0);
            }

            // softmax (no max: K pre-scaled by 0.125, |s| <~ 1 by construction)
            #pragma unroll
            for (int u = 0; u < 2; u++)
                #pragma unroll
                for (int nt = 0; nt < 8; nt++)
                    #pragma unroll
                    for (int r = 0; r < 4; r++) {
                        const float p = __expf(sa[u][nt][r]);
                        lsum[u] += p;
                        sa[u][nt][r] = p;
                    }

            // PV: O^T += V^T · P^T ; P^T B-frags ARE sa regs (pattern-permuted)
            #pragma unroll
            for (int ks = 0; ks < 4; ++ks) {
                Bfrag pB[2];
                #pragma unroll
                for (int u = 0; u < 2; u++) {
                    pB[u].u[0] = pk_hi(sa[u][2 * ks][0],     sa[u][2 * ks][1]);
                    pB[u].u[1] = pk_hi(sa[u][2 * ks][2],     sa[u][2 * ks][3]);
                    pB[u].u[2] = pk_hi(sa[u][2 * ks + 1][0], sa[u][2 * ks + 1][1]);
                    pB[u].u[3] = pk_hi(sa[u][2 * ks + 1][2], sa[u][2 * ks + 1][3]);
                }
                #pragma unroll
                for (int nd = 0; nd < 4; ++nd) {
                    const char* vb = vc + ((nd * 16 + cl) << 8) + (((ks * 4 + g) ^ cl) << 4);
                    const s16x8 av = *(const s16x8*)vb;
                    oacc[0][nd] = __builtin_amdgcn_mfma_f32_16x16x32_bf16(av, pB[0].s, oacc[0][nd], 0, 0, 0);
                    oacc[1][nd] = __builtin_amdgcn_mfma_f32_16x16x32_bf16(av, pB[1].s, oacc[1][nd], 0, 0, 0);
                }
            }
        }

        // normalize + write O (lane's oacc all belong to its query row)
        #pragma unroll
        for (int u = 0; u < 2; ++u) {
            float s = lsum[u];
            s += __shfl_xor(s, 16);
            s += __shfl_xor(s, 32);
            const float inv = 1.f / s;
            const size_t qr = (size_t)(q0 + u * 16);
            #pragma unroll
            for (int nd = 0; nd < 4; ++nd) {
                const float o0 = oacc[u][nd][0] * inv, o1 = oacc[u][nd][1] * inv;
                const float o2 = oacc[u][nd][2] * inv, o3 = oacc[u][nd][3] * inv;
                const unsigned lo = (unsigned)f2bf(o0) | ((unsigned)f2bf(o1) << 16);
                const unsigned hi = (unsigned)f2bf(o2) | ((unsigned)f2bf(o3) << 16);
                short* dst = ao_bf + qr * 512 + h * 64 + nd * 16 + 4 * g;
                *(unsigned*)(dst)     = lo;
                *(unsigned*)(dst + 2) = hi;
            }
        }
    }
}

// ---------------------------------------------------------------- K4: out-proj MFMA + LN
__global__ __launch_bounds__(256, 4)
void outproj_ln_kernel(const short* __restrict__ ao,
                       const short* __restrict__ wout_bf,
                       const float* __restrict__ bout,
                       float* __restrict__ out) {
    __shared__ __align__(16) char smem[33280];       // A[32][520]s16 == ys[32][260]f32
    short* as = (short*)smem;
    float* ys = (float*)smem;
    const int tid = threadIdx.x;
    const int r0 = blockIdx.x * 32;

    #pragma unroll
    for (int it = 0; it < 8; it++) {
        const int idx = tid + it * 256;              // s16x8 index, 2048 total
        const int row = idx >> 6, c8 = idx & 63;
        const s16x8 v = *(const s16x8*)(ao + (size_t)(r0 + row) * 512 + c8 * 8);
        *(s16x8*)(as + row * 520 + c8 * 8) = v;
    }
    __syncthreads();

    const int lane = tid & 63, w = tid >> 6, g = lane >> 4, cl = lane & 15;

    f32x4 acc[2][4];
    #pragma unroll
    for (int mt = 0; mt < 2; mt++)
        #pragma unroll
        for (int nt = 0; nt < 4; nt++) acc[mt][nt] = (f32x4){0.f, 0.f, 0.f, 0.f};

    for (int s = 0; s < 16; s++) {
        const s16x8 a0 = *(const s16x8*)(as + cl * 520 + s * 32 + g * 8);
        const s16x8 a1 = *(const s16x8*)(as + (16 + cl) * 520 + s * 32 + g * 8);
        #pragma unroll
        for (int nt = 0; nt < 4; nt++) {
            const s16x8 b = *(const s16x8*)(wout_bf + (size_t)(w * 64 + nt * 16 + cl) * 512 + s * 32 + g * 8);
            acc[0][nt] = __builtin_amdgcn_mfma_f32_16x16x32_bf16(a0, b, acc[0][nt], 0, 0, 0);
            acc[1][nt] = __builtin_amdgcn_mfma_f32_16x16x32_bf16(a1, b, acc[1][nt], 0, 0, 0);
        }
    }
    __syncthreads();

    #pragma unroll
    for (int nt = 0; nt < 4; nt++) {
        const int col = w * 64 + nt * 16 + cl;
        const float b = bout[col];
        #pragma unroll
        for (int mt = 0; mt < 2; mt++)
            #pragma unroll
            for (int r = 0; r < 4; r++)
                ys[(mt * 16 + g * 4 + r) * 260 + col] = acc[mt][nt][r] + b;
    }
    __syncthreads();

    for (int q = 0; q < 8; q++) {
        const int m = w * 8 + q;
        const float4 v4 = *(const float4*)(ys + m * 260 + lane * 4);
        float s = v4.x + v4.y + v4.z + v4.w;
        #pragma unroll
        for (int off = 32; off; off >>= 1) s += __shfl_xor(s, off);
        const float mu = s * (1.f / 256.f);
        const float d0 = v4.x - mu, d1 = v4.y - mu, d2 = v4.z - mu, d3 = v4.w - mu;
        float vv = d0 * d0 + d1 * d1 + d2 * d2 + d3 * d3;
        #pragma unroll
        for (int off = 32; off; off >>= 1) vv += __shfl_xor(vv, off);
        const float rs = rsqrtf(vv * (1.f / 256.f) + EPSF);
        float4 o; o.x = d0 * rs; o.y = d1 * rs; o.z = d2 * rs; o.w = d3 * rs;
        *(float4*)(out + (size_t)(r0 + m) * 256 + lane * 4) = o;
    }
}

// ---------------------------------------------------------------- launch
extern "C" void kernel_launch(void* const* d_in, const int* in_sizes, int n_in,
                              void* d_out, int out_size, void* d_ws, size_t ws_size,
                              hipStream_t stream) {
    const float* normed_x = (const float*)d_in[0];
    const float* conv_w   = (const float*)d_in[1];
    const float* conv_b   = (const float*)d_in[2];
    const float* pattern  = (const float*)d_in[3];
    const float* wq       = (const float*)d_in[4];
    const float* wkv      = (const float*)d_in[5];
    const float* wout     = (const float*)d_in[6];
    const float* bout     = (const float*)d_in[7];
    const int T = in_sizes[0] / 256;               // 65536

    char* wsb = (char*)d_ws;
    short* xn_bf  = (short*)(wsb);                             // T*256 bf16 = 32 MB
    short* ao_bf  = (short*)(wsb + (size_t)33554432);          // T*512 bf16 = 64 MB
    short* k_bf   = (short*)(wsb + (size_t)100663296);         // 512 KB
    short* v_t    = (short*)(wsb + (size_t)101187584);         // 512 KB
    short* wq_bf  = (short*)(wsb + (size_t)101711872);         // 256 KB
    short* wout_bf= (short*)(wsb + (size_t)101974016);         // 256 KB
    short* wck    = (short*)(wsb + (size_t)102236160);         // 384 KB
    float* out    = (float*)d_out;

    cvt_kernel<<<512, 256, 0, stream>>>(wq, wout, conv_w, wq_bf, wout_bf, wck);
    pat_kv_kernel<<<512, 256, 0, stream>>>(pattern, wkv, k_bf, v_t);
    conv_ln_kernel<<<T / 64, 256, 0, stream>>>(normed_x, wck, conv_b, xn_bf);
    qattn_kernel<<<T / 128, 256, 0, stream>>>(xn_bf, wq_bf, k_bf, v_t, ao_bf);
    outproj_ln_kernel<<<T / 32, 256, 0, stream>>>(ao_bf, wout_bf, bout, out);
}